// Round 9
// baseline (249.953 us; speedup 1.0000x reference)
//
#include <hip/hip_runtime.h>
#include <stdint.h>

typedef float  f32x4  __attribute__((ext_vector_type(4)));
typedef float  f32x16 __attribute__((ext_vector_type(16)));
typedef __bf16 bf16x8 __attribute__((ext_vector_type(8)));
typedef unsigned int   u32;
typedef unsigned int   u32x4v __attribute__((ext_vector_type(4)));
typedef unsigned short u16;

#define DEVI static __device__ __forceinline__

DEVI void gload16(void* lds, const void* g) {
  __builtin_amdgcn_global_load_lds((const __attribute__((address_space(1))) u32*)g,
                                   (__attribute__((address_space(3))) u32*)lds, 16, 0, 0);
}
DEVI f32x4 mfma16(bf16x8 a, bf16x8 b, f32x4 c) {
  return __builtin_amdgcn_mfma_f32_16x16x32_bf16(a, b, c, 0, 0, 0);
}
DEVI f32x16 mfma32(bf16x8 a, bf16x8 b, f32x16 c) {
  return __builtin_amdgcn_mfma_f32_32x32x16_bf16(a, b, c, 0, 0, 0);
}
DEVI u16 f2bf(float f) {  // RNE f32->bf16 (finite inputs)
  u32 u = __builtin_bit_cast(u32, f);
  return (u16)((u + 0x7FFFu + ((u >> 16) & 1u)) >> 16);
}
DEVI u32 cvtpk(float lo, float hi) {  // packed f32->bf16 pair, lo in [15:0]
  u32 r;
  asm("v_cvt_pk_bf16_f32 %0, %1, %2" : "=v"(r) : "v"(lo), "v"(hi));
  return r;
}
DEVI bf16x8 mkfrag(u32 a, u32 b, u32 c, u32 d) {
  u32x4v u = {a, b, c, d};
  return __builtin_bit_cast(bf16x8, u);
}
#if __has_builtin(__builtin_amdgcn_exp2f)
DEVI float exp2fast(float x) { return __builtin_amdgcn_exp2f(x); }
#else
DEVI float exp2fast(float x) { return exp2f(x); }
#endif

// ---------------- GroupNorm stats: one block per (b,g); 64ch*1024 = 65536 contiguous f32
__global__ __launch_bounds__(256) void k_gnstats(const float* __restrict__ x,
                                                 float* __restrict__ meanr) {
  const int bg = blockIdx.x;
  const float4* p4 = (const float4*)(x + (size_t)bg * 65536);
  const int t = threadIdx.x;
  float s = 0.f, ss = 0.f;
  for (int i = t; i < 16384; i += 256) {
    float4 v = p4[i];
    s  += v.x + v.y + v.z + v.w;
    ss += v.x*v.x + v.y*v.y + v.z*v.z + v.w*v.w;
  }
  for (int off = 32; off; off >>= 1) { s += __shfl_down(s, off); ss += __shfl_down(ss, off); }
  __shared__ float sa[4], sb[4];
  const int w = t >> 6;
  if ((t & 63) == 0) { sa[w] = s; sb[w] = ss; }
  __syncthreads();
  if (t == 0) {
    float S = sa[0]+sa[1]+sa[2]+sa[3], SS = sb[0]+sb[1]+sb[2]+sb[3];
    float mean = S * (1.f/65536.f);
    float var  = SS * (1.f/65536.f) - mean*mean;
    meanr[2*bg]   = mean;
    meanr[2*bg+1] = rsqrtf(var + 1e-5f);
  }
}

// ---------------- f32 -> bf16 weight convert
__global__ __launch_bounds__(256) void k_cvt(const float* __restrict__ a,
                                             u16* __restrict__ o, int n) {
  int i = blockIdx.x * 256 + threadIdx.x;
  const int stride = gridDim.x * 256;
  for (; i < n; i += stride) o[i] = f2bf(a[i]);
}

// ---------------- normalize + transpose: x[b][c][n] f32 -> xnT[b][n][c] bf16
__global__ __launch_bounds__(256) void k_norm_t(
    const float* __restrict__ x, const float* __restrict__ meanr,
    const float* __restrict__ scale, const float* __restrict__ bias,
    u16* __restrict__ xnT) {
  __shared__ __align__(16) char T[8192];   // [64 n][64 c] bf16, 16B-slot XOR swizzle
  const int t = threadIdx.x;
  const int nt = blockIdx.x, ct = blockIdx.y, b = blockIdx.z;
  const int n0 = nt*64, c0 = ct*64;
  const float mean = meanr[2*(b*8 + ct)];
  const float rstd = meanr[2*(b*8 + ct) + 1];
  const int n_l = t & 63;
  const float* xb = x + ((size_t)b*512 + c0)*1024 + n0;
  #pragma unroll
  for (int i = 0; i < 16; i++) {
    int c_l = i*4 + (t>>6);
    float xv = xb[(size_t)c_l*1024 + n_l];
    float val = (xv - mean)*rstd*scale[c0+c_l] + bias[c0+c_l];
    *(u16*)(T + n_l*128 + ((c_l*2) ^ ((n_l&7)<<4))) = f2bf(val);
  }
  __syncthreads();
  u16* outp = xnT + ((size_t)b*1024 + n0)*512 + c0;
  #pragma unroll
  for (int i = 0; i < 2; i++) {
    int idx = i*256 + t;
    int n_ = idx >> 3, s = idx & 7;
    uint4 val = *(const uint4*)(T + n_*128 + ((s ^ (n_&7))<<4));
    *(uint4*)((char*)outp + (size_t)n_*1024 + s*16) = val;
  }
}

// ---------------- GEMM: C[128m x 128n] = A[M][512] * Bt[n][512]^T, per-batch B
// 2-phase LDS double-buffer: stage(t+1) issued before compute(t); 1 barrier/step.
// MODE 0: qkv -> q/k transposed [b][h][n][64] (q scaled 1/8*log2e), v natural [b][h][64][n]
// MODE 1: proj -> out = C + bias + residual (f32)
template<int MODE>
__global__ __launch_bounds__(256) void k_gemm(
    const u16* __restrict__ A, const u16* __restrict__ Bt,
    const float* __restrict__ bias, const float* __restrict__ xres,
    u16* __restrict__ oq, u16* __restrict__ ok, u16* __restrict__ ov,
    float* __restrict__ out) {
  __shared__ __align__(16) char lds[65536];   // 2 x (A 16K | B 16K); epilogue reuses 32K
  const int t = threadIdx.x;
  const int wv = t >> 6, ln = t & 63;
  const int wr = wv >> 1, wc = wv & 1;
  const int b  = blockIdx.z;
  const int n0 = blockIdx.x * 128;
  const int m0 = blockIdx.y * 128;
  const u16* Bb = Bt + (size_t)b * (1024*512);

  f32x4 acc[4][4];
  #pragma unroll
  for (int i = 0; i < 4; i++)
    #pragma unroll
    for (int j = 0; j < 4; j++) acc[i][j] = f32x4{0.f,0.f,0.f,0.f};

  const int srow = ln >> 3, ssl = ln & 7;
  const int csw  = ssl ^ (srow & 7);          // pre-swizzled source slot

  auto stage = [&](int buf, int kb) {
    char* base = lds + (buf << 15);
    #pragma unroll
    for (int i = 0; i < 4; i++) {
      int row = wv*32 + i*8 + srow;
      gload16(base + (wv*32 + i*8)*128,
              (const char*)A  + ((size_t)(m0+row)*512 + kb*64)*2 + csw*16);
      gload16(base + 16384 + (wv*32 + i*8)*128,
              (const char*)Bb + ((size_t)(n0+row)*512 + kb*64)*2 + csw*16);
    }
  };

  stage(0, 0);
  __syncthreads();                            // buf0 staged (drains vmcnt)

  for (int kb = 0; kb < 8; kb++) {            // K = 512, BK = 64
    if (kb < 7) stage((kb + 1) & 1, kb + 1);  // issue next tile into other buf
    const char* cb = lds + ((kb & 1) << 15);
    #pragma unroll
    for (int kf = 0; kf < 2; kf++) {
      bf16x8 af[4], bfr[4];
      #pragma unroll
      for (int mi = 0; mi < 4; mi++) {
        int row = wr*64 + mi*16 + (ln & 15);
        af[mi] = *(const bf16x8*)(cb + row*128 + ((kf*64 + ((ln>>4)<<4)) ^ ((row&7)<<4)));
      }
      #pragma unroll
      for (int ni = 0; ni < 4; ni++) {
        int row = wc*64 + ni*16 + (ln & 15);
        bfr[ni] = *(const bf16x8*)(cb + 16384 + row*128 + ((kf*64 + ((ln>>4)<<4)) ^ ((row&7)<<4)));
      }
      __builtin_amdgcn_s_setprio(1);
      #pragma unroll
      for (int mi = 0; mi < 4; mi++)
        #pragma unroll
        for (int ni = 0; ni < 4; ni++)
          acc[mi][ni] = mfma16(af[mi], bfr[ni], acc[mi][ni]);
      __builtin_amdgcn_s_setprio(0);
    }
    __syncthreads();                          // next buf staged; cur buf free
  }

  if constexpr (MODE == 0) {
    if (m0 >= 1024) {                          // V: natural [b][512=h*64+d][1024]
      #pragma unroll
      for (int mi = 0; mi < 4; mi++) {
        #pragma unroll
        for (int r = 0; r < 4; r++) {
          int o_l = wr*64 + mi*16 + ((ln>>4)<<2) + r;
          float bia = bias[m0 + o_l];
          size_t rowoff = ((size_t)b*512 + (m0-1024) + o_l)*1024 + n0 + wc*64 + (ln & 15);
          #pragma unroll
          for (int ni = 0; ni < 4; ni++)
            ov[rowoff + ni*16] = f2bf(acc[mi][ni][r] + bia);
        }
      }
    } else {                                   // Q/K: transpose via LDS -> [b][h][n][64]
      const bool isq = (m0 < 512);
      const float sq = isq ? 0.18033688f : 1.0f;  // d^-0.5 * log2(e) folded into q
      u16* dstb = isq ? oq : ok;
      const int mloc = isq ? m0 : (m0 - 512);
      #pragma unroll
      for (int mi = 0; mi < 4; mi++) {
        #pragma unroll
        for (int r = 0; r < 4; r++) {
          int o_l = wr*64 + mi*16 + ((ln>>4)<<2) + r;
          float bia = bias[m0 + o_l];
          #pragma unroll
          for (int ni = 0; ni < 4; ni++) {
            int n_l = wc*64 + ni*16 + (ln & 15);
            *(u16*)(lds + n_l*256 + ((o_l*2) ^ ((n_l&7)<<4))) =
                f2bf((acc[mi][ni][r] + bia) * sq);
          }
        }
      }
      __syncthreads();
      const int h0 = mloc >> 6;                // 2 heads per 128-row tile
      #pragma unroll
      for (int i = 0; i < 8; i++) {
        int idx = i*256 + t;
        int n_ = idx >> 4, s = idx & 15;
        uint4 val = *(const uint4*)(lds + n_*256 + ((s ^ (n_&7))<<4));
        u16* dst = dstb + ((size_t)(b*8 + h0 + (s>>3))*1024 + (n0 + n_))*64 + (s&7)*8;
        *(uint4*)dst = val;
      }
    }
  } else {                                     // proj: + bias + residual, f32 out
    #pragma unroll
    for (int mi = 0; mi < 4; mi++) {
      #pragma unroll
      for (int r = 0; r < 4; r++) {
        int o_l = wr*64 + mi*16 + ((ln>>4)<<2) + r;
        float bia = bias[m0 + o_l];
        size_t rowoff = ((size_t)b*512 + m0 + o_l)*1024 + n0 + wc*64 + (ln & 15);
        #pragma unroll
        for (int ni = 0; ni < 4; ni++)
          out[rowoff + ni*16] = acc[mi][ni][r] + bia + xres[rowoff + ni*16];
      }
    }
  }
}

// ---------------- flash attention, swapped-QK^T 32x32 form, 8 waves.
// R9 (T15): per 128-key round the two 64-key bodies are phase-interleaved in
// ONE schedulable region: QK_A -> SM_A -> QK_B -> PV_A -> SM_B -> PV_B, so
// QK_B's MFMAs hoist into SM_A's exp/sum VALU stream and PV_A runs under
// SM_B's fmax/exp — the wave fills its own dependency stalls.
__global__ __launch_bounds__(512, 4) void k_attn(
    const u16* __restrict__ qT, const u16* __restrict__ kT,
    const u16* __restrict__ v, u16* __restrict__ aoT) {
  __shared__ __align__(16) char lds[65536];    // 2 bufs x (K_A|K_B|V_A|V_B) x 8KB
  const int t = threadIdx.x, wv = t >> 6, ln = t & 63;
  const int l31 = ln & 31, hi = ln >> 5;
  const int qt = blockIdx.x, h = blockIdx.y, b = blockIdx.z;
  const size_t bh = (size_t)(b*8 + h);
  const int q0 = qt*256 + wv*32;
  const char* qp = (const char*)qT + (bh*1024 + q0)*128;
  const char* kp = (const char*)kT + bh*1024*128;
  const char* vp = (const char*)v  + bh*64*2048;

  const int srow = ln >> 3;
  const int csw16 = ((ln & 7) ^ srow) << 4;    // pre-swizzled source slot (bytes)
  const int rsw = (l31 & 7) << 4;              // read-side swizzle for this lane's rows
  const int grow = wv*8 + srow;                // this thread's staging row (0..63)

  auto stageChunk = [&](char* base, int mc) {  // one 128-key chunk (4 gload16/thread)
    gload16(base + wv*1024,         kp + (size_t)(mc*128 + grow)*128 + csw16);
    gload16(base + 8192 + wv*1024,  kp + (size_t)(mc*128 + 64 + grow)*128 + csw16);
    gload16(base + 16384 + wv*1024, vp + (size_t)grow*2048 + mc*256 + csw16);
    gload16(base + 24576 + wv*1024, vp + (size_t)grow*2048 + mc*256 + 128 + csw16);
  };

  // prologue: stage chunk 0 into buf 0
  stageChunk(lds, 0);

  bf16x8 qf[4];                                // Q B-frags: col=q(lane&31), k=d
  #pragma unroll
  for (int ks = 0; ks < 4; ks++)
    qf[ks] = *(const bf16x8*)(qp + (size_t)l31*128 + ks*32 + hi*16);

  f32x16 o0, o1;                               // O^T accum
  #pragma unroll
  for (int i = 0; i < 16; i++) { o0[i] = 0.f; o1[i] = 0.f; }
  float M = -1e30f, L = 0.f;                   // L is own-half partial until epilogue

  // QK^T for one 64-key half
  auto qk = [&](const char* Kl, f32x16& s0, f32x16& s1) {
    #pragma unroll
    for (int i = 0; i < 16; i++) { s0[i] = 0.f; s1[i] = 0.f; }
    __builtin_amdgcn_s_setprio(1);
    #pragma unroll
    for (int ks = 0; ks < 4; ks++) {
      int col = (ks*32 + hi*16) ^ rsw;
      bf16x8 k0 = *(const bf16x8*)(Kl + (size_t)l31*128 + col);
      bf16x8 k1 = *(const bf16x8*)(Kl + (size_t)(32 + l31)*128 + col);
      s0 = mfma32(k0, qf[ks], s0);
      s1 = mfma32(k1, qf[ks], s1);
    }
    __builtin_amdgcn_s_setprio(0);
  };

  // softmax + P->bf16 frags for one half (updates M, L, rescales o on demand)
  auto sm = [&](f32x16& s0, f32x16& s1, bf16x8* pf) {
    float m8[8];
    #pragma unroll
    for (int i = 0; i < 8; i++)
      m8[i] = fmaxf(fmaxf(s0[2*i], s0[2*i+1]), fmaxf(s1[2*i], s1[2*i+1]));
    float m4a = fmaxf(m8[0], m8[1]), m4b = fmaxf(m8[2], m8[3]);
    float m4c = fmaxf(m8[4], m8[5]), m4d = fmaxf(m8[6], m8[7]);
    float cm = fmaxf(fmaxf(m4a, m4b), fmaxf(m4c, m4d));
    cm = fmaxf(cm, __shfl_xor(cm, 32));
    if (!__all(cm <= M + 11.f)) {              // defer-max: P bounded by 2^11
      float nm = fmaxf(M, cm);
      float al = exp2fast(M - nm);
      M = nm;
      #pragma unroll
      for (int i = 0; i < 16; i++) { o0[i] *= al; o1[i] *= al; }
      L *= al;
    }
    #pragma unroll
    for (int i = 0; i < 16; i++) {
      s0[i] = exp2fast(s0[i] - M);
      s1[i] = exp2fast(s1[i] - M);
    }
    float r8[8];
    #pragma unroll
    for (int i = 0; i < 8; i++)
      r8[i] = (s0[2*i] + s0[2*i+1]) + (s1[2*i] + s1[2*i+1]);
    float r4a = r8[0] + r8[1], r4b = r8[2] + r8[3];
    float r4c = r8[4] + r8[5], r4d = r8[6] + r8[7];
    L += (r4a + r4b) + (r4c + r4d);            // own-half partial only

    u32 x0 = cvtpk(s0[0],  s0[1]),  x1 = cvtpk(s0[2],  s0[3]);
    u32 x2 = cvtpk(s0[4],  s0[5]),  x3 = cvtpk(s0[6],  s0[7]);
    u32 x4 = cvtpk(s0[8],  s0[9]),  x5 = cvtpk(s0[10], s0[11]);
    u32 x6 = cvtpk(s0[12], s0[13]), x7 = cvtpk(s0[14], s0[15]);
    u32 y0 = cvtpk(s1[0],  s1[1]),  y1 = cvtpk(s1[2],  s1[3]);
    u32 y2 = cvtpk(s1[4],  s1[5]),  y3 = cvtpk(s1[6],  s1[7]);
    u32 y4 = cvtpk(s1[8],  s1[9]),  y5 = cvtpk(s1[10], s1[11]);
    u32 y6 = cvtpk(s1[12], s1[13]), y7 = cvtpk(s1[14], s1[15]);
    u32 x0p = __shfl_xor((int)x0, 32), x1p = __shfl_xor((int)x1, 32);
    u32 x2p = __shfl_xor((int)x2, 32), x3p = __shfl_xor((int)x3, 32);
    u32 x4p = __shfl_xor((int)x4, 32), x5p = __shfl_xor((int)x5, 32);
    u32 x6p = __shfl_xor((int)x6, 32), x7p = __shfl_xor((int)x7, 32);
    u32 y0p = __shfl_xor((int)y0, 32), y1p = __shfl_xor((int)y1, 32);
    u32 y2p = __shfl_xor((int)y2, 32), y3p = __shfl_xor((int)y3, 32);
    u32 y4p = __shfl_xor((int)y4, 32), y5p = __shfl_xor((int)y5, 32);
    u32 y6p = __shfl_xor((int)y6, 32), y7p = __shfl_xor((int)y7, 32);
    pf[0] = hi ? mkfrag(x2p, x3p, x2, x3) : mkfrag(x0, x1, x0p, x1p);
    pf[1] = hi ? mkfrag(x6p, x7p, x6, x7) : mkfrag(x4, x5, x4p, x5p);
    pf[2] = hi ? mkfrag(y2p, y3p, y2, y3) : mkfrag(y0, y1, y0p, y1p);
    pf[3] = hi ? mkfrag(y6p, y7p, y6, y7) : mkfrag(y4, y5, y4p, y5p);
  };

  auto pv = [&](const char* Vl, const bf16x8* pf) {
    __builtin_amdgcn_s_setprio(1);
    #pragma unroll
    for (int s = 0; s < 4; s++) {
      int col = (s*32 + hi*16) ^ rsw;
      bf16x8 v0 = *(const bf16x8*)(Vl + (size_t)l31*128 + col);
      bf16x8 v1 = *(const bf16x8*)(Vl + (size_t)(32 + l31)*128 + col);
      o0 = mfma32(v0, pf[s], o0);
      o1 = mfma32(v1, pf[s], o1);
    }
    __builtin_amdgcn_s_setprio(0);
  };

  __syncthreads();                             // chunk 0 staged (drains vmcnt)

  for (int mc = 0; mc < 8; mc++) {             // 8 rounds of 128 keys
    char* cb = lds + ((mc & 1) << 15);
    if (mc < 7) stageChunk(lds + (((mc + 1) & 1) << 15), mc + 1);
    f32x16 sa0, sa1, sb0, sb1;
    bf16x8 pfA[4], pfB[4];
    qk(cb, sa0, sa1);                          // QK_A
    sm(sa0, sa1, pfA);                         // SM_A  (sa dies here)
    qk(cb + 8192, sb0, sb1);                   // QK_B — hoists into SM_A's VALU
    pv(cb + 16384, pfA);                       // PV_A — overlaps SM_B below
    sm(sb0, sb1, pfB);                         // SM_B
    pv(cb + 24576, pfB);                       // PV_B
    __syncthreads();                           // releases cur buf, publishes next buf
  }

  // ---- epilogue: merge cross-half L, then O/L -> aoT[b][n][c=h*64+d] bf16 ----
  L += __shfl_xor(L, 32);
  float inv = 1.f / L;
  u16* dst = aoT + ((size_t)(b*1024 + q0 + l31))*512 + h*64;
  #pragma unroll
  for (int qd = 0; qd < 4; qd++) {
    uint2 val;
    val.x = cvtpk(o0[4*qd+0]*inv, o0[4*qd+1]*inv);
    val.y = cvtpk(o0[4*qd+2]*inv, o0[4*qd+3]*inv);
    *(uint2*)(dst + qd*8 + hi*4) = val;
  }
  #pragma unroll
  for (int qd = 0; qd < 4; qd++) {
    uint2 val;
    val.x = cvtpk(o1[4*qd+0]*inv, o1[4*qd+1]*inv);
    val.y = cvtpk(o1[4*qd+2]*inv, o1[4*qd+3]*inv);
    *(uint2*)(dst + 32 + qd*8 + hi*4) = val;
  }
}

extern "C" void kernel_launch(void* const* d_in, const int* in_sizes, int n_in,
                              void* d_out, int out_size, void* d_ws, size_t ws_size,
                              hipStream_t stream) {
  const float* x     = (const float*)d_in[0];
  const float* nsc   = (const float*)d_in[1];
  const float* nbi   = (const float*)d_in[2];
  const float* qkvw  = (const float*)d_in[3];
  const float* qkvb  = (const float*)d_in[4];
  const float* projw = (const float*)d_in[5];
  const float* projb = (const float*)d_in[6];
  float* out = (float*)d_out;

  char* ws = (char*)d_ws;
  float* meanr = (float*)ws;                          // 2 KB
  u16* qkvwb  = (u16*)(ws + 2048);                    // 1536*512*2
  u16* projwb = (u16*)(ws + 2048 + 1572864);          // 512*512*2
  char* p = ws + 2048 + 1572864 + 524288;
  u16* qT  = (u16*)p; p += 33554432;                  // [b][h][1024][64] bf16 (scaled)
  u16* kTb = (u16*)p; p += 33554432;                  // [b][h][1024][64] bf16
  u16* vb  = (u16*)p; p += 33554432;                  // [b][h][64][1024] bf16
  u16* xnT = (u16*)p;                                 // [b][1024][512] bf16, reused as aoT
  u16* aoT = xnT;

  k_gnstats<<<256, 256, 0, stream>>>(x, meanr);
  k_cvt<<<768, 256, 0, stream>>>(qkvw, qkvwb, 1536*512);
  k_cvt<<<256, 256, 0, stream>>>(projw, projwb, 512*512);
  k_norm_t<<<dim3(16, 8, 32), 256, 0, stream>>>(x, meanr, nsc, nbi, xnT);
  k_gemm<0><<<dim3(8, 12, 32), 256, 0, stream>>>(qkvwb, xnT, qkvb, nullptr,
                                                 qT, kTb, vb, nullptr);
  k_attn<<<dim3(4, 8, 32), 512, 0, stream>>>(qT, kTb, vb, aoT);
  k_gemm<1><<<dim3(8, 4, 32), 256, 0, stream>>>(projwb, aoT, projb, x,
                                                nullptr, nullptr, nullptr, out);
}

// Round 10
// 245.277 us; speedup vs baseline: 1.0191x; 1.0191x over previous
//
#include <hip/hip_runtime.h>
#include <stdint.h>

typedef float  f32x4  __attribute__((ext_vector_type(4)));
typedef float  f32x16 __attribute__((ext_vector_type(16)));
typedef __bf16 bf16x8 __attribute__((ext_vector_type(8)));
typedef unsigned int   u32;
typedef unsigned int   u32x4v __attribute__((ext_vector_type(4)));
typedef unsigned short u16;

#define DEVI static __device__ __forceinline__

DEVI void gload16(void* lds, const void* g) {
  __builtin_amdgcn_global_load_lds((const __attribute__((address_space(1))) u32*)g,
                                   (__attribute__((address_space(3))) u32*)lds, 16, 0, 0);
}
DEVI f32x4 mfma16(bf16x8 a, bf16x8 b, f32x4 c) {
  return __builtin_amdgcn_mfma_f32_16x16x32_bf16(a, b, c, 0, 0, 0);
}
DEVI f32x16 mfma32(bf16x8 a, bf16x8 b, f32x16 c) {
  return __builtin_amdgcn_mfma_f32_32x32x16_bf16(a, b, c, 0, 0, 0);
}
DEVI u16 f2bf(float f) {  // RNE f32->bf16 (finite inputs)
  u32 u = __builtin_bit_cast(u32, f);
  return (u16)((u + 0x7FFFu + ((u >> 16) & 1u)) >> 16);
}
DEVI u32 cvtpk(float lo, float hi) {  // packed f32->bf16 pair, lo in [15:0]
  u32 r;
  asm("v_cvt_pk_bf16_f32 %0, %1, %2" : "=v"(r) : "v"(lo), "v"(hi));
  return r;
}
DEVI bf16x8 mkfrag(u32 a, u32 b, u32 c, u32 d) {
  u32x4v u = {a, b, c, d};
  return __builtin_bit_cast(bf16x8, u);
}
#if __has_builtin(__builtin_amdgcn_exp2f)
DEVI float exp2fast(float x) { return __builtin_amdgcn_exp2f(x); }
#else
DEVI float exp2fast(float x) { return exp2f(x); }
#endif

// ---------------- GroupNorm stats: one block per (b,g); 64ch*1024 = 65536 contiguous f32
__global__ __launch_bounds__(256) void k_gnstats(const float* __restrict__ x,
                                                 float* __restrict__ meanr) {
  const int bg = blockIdx.x;
  const float4* p4 = (const float4*)(x + (size_t)bg * 65536);
  const int t = threadIdx.x;
  float s = 0.f, ss = 0.f;
  for (int i = t; i < 16384; i += 256) {
    float4 v = p4[i];
    s  += v.x + v.y + v.z + v.w;
    ss += v.x*v.x + v.y*v.y + v.z*v.z + v.w*v.w;
  }
  for (int off = 32; off; off >>= 1) { s += __shfl_down(s, off); ss += __shfl_down(ss, off); }
  __shared__ float sa[4], sb[4];
  const int w = t >> 6;
  if ((t & 63) == 0) { sa[w] = s; sb[w] = ss; }
  __syncthreads();
  if (t == 0) {
    float S = sa[0]+sa[1]+sa[2]+sa[3], SS = sb[0]+sb[1]+sb[2]+sb[3];
    float mean = S * (1.f/65536.f);
    float var  = SS * (1.f/65536.f) - mean*mean;
    meanr[2*bg]   = mean;
    meanr[2*bg+1] = rsqrtf(var + 1e-5f);
  }
}

// ---------------- f32 -> bf16 weight convert
__global__ __launch_bounds__(256) void k_cvt(const float* __restrict__ a,
                                             u16* __restrict__ o, int n) {
  int i = blockIdx.x * 256 + threadIdx.x;
  const int stride = gridDim.x * 256;
  for (; i < n; i += stride) o[i] = f2bf(a[i]);
}

// ---------------- normalize + transpose: x[b][c][n] f32 -> xnT[b][n][c] bf16
__global__ __launch_bounds__(256) void k_norm_t(
    const float* __restrict__ x, const float* __restrict__ meanr,
    const float* __restrict__ scale, const float* __restrict__ bias,
    u16* __restrict__ xnT) {
  __shared__ __align__(16) char T[8192];   // [64 n][64 c] bf16, 16B-slot XOR swizzle
  const int t = threadIdx.x;
  const int nt = blockIdx.x, ct = blockIdx.y, b = blockIdx.z;
  const int n0 = nt*64, c0 = ct*64;
  const float mean = meanr[2*(b*8 + ct)];
  const float rstd = meanr[2*(b*8 + ct) + 1];
  const int n_l = t & 63;
  const float* xb = x + ((size_t)b*512 + c0)*1024 + n0;
  #pragma unroll
  for (int i = 0; i < 16; i++) {
    int c_l = i*4 + (t>>6);
    float xv = xb[(size_t)c_l*1024 + n_l];
    float val = (xv - mean)*rstd*scale[c0+c_l] + bias[c0+c_l];
    *(u16*)(T + n_l*128 + ((c_l*2) ^ ((n_l&7)<<4))) = f2bf(val);
  }
  __syncthreads();
  u16* outp = xnT + ((size_t)b*1024 + n0)*512 + c0;
  #pragma unroll
  for (int i = 0; i < 2; i++) {
    int idx = i*256 + t;
    int n_ = idx >> 3, s = idx & 7;
    uint4 val = *(const uint4*)(T + n_*128 + ((s ^ (n_&7))<<4));
    *(uint4*)((char*)outp + (size_t)n_*1024 + s*16) = val;
  }
}

// ---------------- GEMM: C[128m x 128n] = A[M][512] * Bt[n][512]^T, per-batch B
// 2-phase LDS double-buffer: stage(t+1) issued before compute(t); 1 barrier/step.
// MODE 0: qkv -> q/k transposed [b][h][n][64] (q scaled 1/8*log2e), v natural [b][h][64][n]
// MODE 1: proj -> out = C + bias + residual (f32)
template<int MODE>
__global__ __launch_bounds__(256) void k_gemm(
    const u16* __restrict__ A, const u16* __restrict__ Bt,
    const float* __restrict__ bias, const float* __restrict__ xres,
    u16* __restrict__ oq, u16* __restrict__ ok, u16* __restrict__ ov,
    float* __restrict__ out) {
  __shared__ __align__(16) char lds[65536];   // 2 x (A 16K | B 16K); epilogue reuses 32K
  const int t = threadIdx.x;
  const int wv = t >> 6, ln = t & 63;
  const int wr = wv >> 1, wc = wv & 1;
  const int b  = blockIdx.z;
  const int n0 = blockIdx.x * 128;
  const int m0 = blockIdx.y * 128;
  const u16* Bb = Bt + (size_t)b * (1024*512);

  f32x4 acc[4][4];
  #pragma unroll
  for (int i = 0; i < 4; i++)
    #pragma unroll
    for (int j = 0; j < 4; j++) acc[i][j] = f32x4{0.f,0.f,0.f,0.f};

  const int srow = ln >> 3, ssl = ln & 7;
  const int csw  = ssl ^ (srow & 7);          // pre-swizzled source slot

  auto stage = [&](int buf, int kb) {
    char* base = lds + (buf << 15);
    #pragma unroll
    for (int i = 0; i < 4; i++) {
      int row = wv*32 + i*8 + srow;
      gload16(base + (wv*32 + i*8)*128,
              (const char*)A  + ((size_t)(m0+row)*512 + kb*64)*2 + csw*16);
      gload16(base + 16384 + (wv*32 + i*8)*128,
              (const char*)Bb + ((size_t)(n0+row)*512 + kb*64)*2 + csw*16);
    }
  };

  stage(0, 0);
  __syncthreads();                            // buf0 staged (drains vmcnt)

  for (int kb = 0; kb < 8; kb++) {            // K = 512, BK = 64
    if (kb < 7) stage((kb + 1) & 1, kb + 1);  // issue next tile into other buf
    const char* cb = lds + ((kb & 1) << 15);
    #pragma unroll
    for (int kf = 0; kf < 2; kf++) {
      bf16x8 af[4], bfr[4];
      #pragma unroll
      for (int mi = 0; mi < 4; mi++) {
        int row = wr*64 + mi*16 + (ln & 15);
        af[mi] = *(const bf16x8*)(cb + row*128 + ((kf*64 + ((ln>>4)<<4)) ^ ((row&7)<<4)));
      }
      #pragma unroll
      for (int ni = 0; ni < 4; ni++) {
        int row = wc*64 + ni*16 + (ln & 15);
        bfr[ni] = *(const bf16x8*)(cb + 16384 + row*128 + ((kf*64 + ((ln>>4)<<4)) ^ ((row&7)<<4)));
      }
      __builtin_amdgcn_s_setprio(1);
      #pragma unroll
      for (int mi = 0; mi < 4; mi++)
        #pragma unroll
        for (int ni = 0; ni < 4; ni++)
          acc[mi][ni] = mfma16(af[mi], bfr[ni], acc[mi][ni]);
      __builtin_amdgcn_s_setprio(0);
    }
    __syncthreads();                          // next buf staged; cur buf free
  }

  if constexpr (MODE == 0) {
    if (m0 >= 1024) {                          // V: natural [b][512=h*64+d][1024]
      #pragma unroll
      for (int mi = 0; mi < 4; mi++) {
        #pragma unroll
        for (int r = 0; r < 4; r++) {
          int o_l = wr*64 + mi*16 + ((ln>>4)<<2) + r;
          float bia = bias[m0 + o_l];
          size_t rowoff = ((size_t)b*512 + (m0-1024) + o_l)*1024 + n0 + wc*64 + (ln & 15);
          #pragma unroll
          for (int ni = 0; ni < 4; ni++)
            ov[rowoff + ni*16] = f2bf(acc[mi][ni][r] + bia);
        }
      }
    } else {                                   // Q/K: transpose via LDS -> [b][h][n][64]
      const bool isq = (m0 < 512);
      const float sq = isq ? 0.18033688f : 1.0f;  // d^-0.5 * log2(e) folded into q
      u16* dstb = isq ? oq : ok;
      const int mloc = isq ? m0 : (m0 - 512);
      #pragma unroll
      for (int mi = 0; mi < 4; mi++) {
        #pragma unroll
        for (int r = 0; r < 4; r++) {
          int o_l = wr*64 + mi*16 + ((ln>>4)<<2) + r;
          float bia = bias[m0 + o_l];
          #pragma unroll
          for (int ni = 0; ni < 4; ni++) {
            int n_l = wc*64 + ni*16 + (ln & 15);
            *(u16*)(lds + n_l*256 + ((o_l*2) ^ ((n_l&7)<<4))) =
                f2bf((acc[mi][ni][r] + bia) * sq);
          }
        }
      }
      __syncthreads();
      const int h0 = mloc >> 6;                // 2 heads per 128-row tile
      #pragma unroll
      for (int i = 0; i < 8; i++) {
        int idx = i*256 + t;
        int n_ = idx >> 4, s = idx & 15;
        uint4 val = *(const uint4*)(lds + n_*256 + ((s ^ (n_&7))<<4));
        u16* dst = dstb + ((size_t)(b*8 + h0 + (s>>3))*1024 + (n0 + n_))*64 + (s&7)*8;
        *(uint4*)dst = val;
      }
    }
  } else {                                     // proj: + bias + residual, f32 out
    #pragma unroll
    for (int mi = 0; mi < 4; mi++) {
      #pragma unroll
      for (int r = 0; r < 4; r++) {
        int o_l = wr*64 + mi*16 + ((ln>>4)<<2) + r;
        float bia = bias[m0 + o_l];
        size_t rowoff = ((size_t)b*512 + m0 + o_l)*1024 + n0 + wc*64 + (ln & 15);
        #pragma unroll
        for (int ni = 0; ni < 4; ni++)
          out[rowoff + ni*16] = acc[mi][ni][r] + bia + xres[rowoff + ni*16];
      }
    }
  }
}

// ---------------- flash attention, swapped-QK^T 32x32 form, 8 waves.
// R10: LDS-pipe-bound per the R9 model, so cut LDS ops:
//  - packed one-direction P-exchange: shfl_xor(hi?xA:xB) serves BOTH halves
//    with one bpermute -> 16->8 exchange shfls per 64-key body.
//  - persistent zero f32x16 as MFMA C-operand (no per-body accumulator init).
__global__ __launch_bounds__(512, 4) void k_attn(
    const u16* __restrict__ qT, const u16* __restrict__ kT,
    const u16* __restrict__ v, u16* __restrict__ aoT) {
  __shared__ __align__(16) char lds[65536];    // 2 bufs x (K_A|K_B|V_A|V_B) x 8KB
  const int t = threadIdx.x, wv = t >> 6, ln = t & 63;
  const int l31 = ln & 31, hi = ln >> 5;
  const int qt = blockIdx.x, h = blockIdx.y, b = blockIdx.z;
  const size_t bh = (size_t)(b*8 + h);
  const int q0 = qt*256 + wv*32;
  const char* qp = (const char*)qT + (bh*1024 + q0)*128;
  const char* kp = (const char*)kT + bh*1024*128;
  const char* vp = (const char*)v  + bh*64*2048;

  const int srow = ln >> 3;
  const int csw16 = ((ln & 7) ^ srow) << 4;    // pre-swizzled source slot (bytes)
  const int rsw = (l31 & 7) << 4;              // read-side swizzle for this lane's rows
  const int grow = wv*8 + srow;                // this thread's staging row (0..63)

  auto stageChunk = [&](char* base, int mc) {  // one 128-key chunk (4 gload16/thread)
    gload16(base + wv*1024,         kp + (size_t)(mc*128 + grow)*128 + csw16);
    gload16(base + 8192 + wv*1024,  kp + (size_t)(mc*128 + 64 + grow)*128 + csw16);
    gload16(base + 16384 + wv*1024, vp + (size_t)grow*2048 + mc*256 + csw16);
    gload16(base + 24576 + wv*1024, vp + (size_t)grow*2048 + mc*256 + 128 + csw16);
  };

  // prologue: stage chunk 0 into buf 0
  stageChunk(lds, 0);

  bf16x8 qf[4];                                // Q B-frags: col=q(lane&31), k=d
  #pragma unroll
  for (int ks = 0; ks < 4; ks++)
    qf[ks] = *(const bf16x8*)(qp + (size_t)l31*128 + ks*32 + hi*16);

  f32x16 zv;                                   // persistent zero C-operand
  #pragma unroll
  for (int i = 0; i < 16; i++) zv[i] = 0.f;

  f32x16 o0, o1;                               // O^T accum
  #pragma unroll
  for (int i = 0; i < 16; i++) { o0[i] = 0.f; o1[i] = 0.f; }
  float M = -1e30f, L = 0.f;                   // L is own-half partial until epilogue

  // QK^T for one 64-key half (no accumulator init: first MFMA uses zv)
  auto qk = [&](const char* Kl, f32x16& s0, f32x16& s1) {
    __builtin_amdgcn_s_setprio(1);
    {
      int col = (hi*16) ^ rsw;
      bf16x8 k0 = *(const bf16x8*)(Kl + (size_t)l31*128 + col);
      bf16x8 k1 = *(const bf16x8*)(Kl + (size_t)(32 + l31)*128 + col);
      s0 = mfma32(k0, qf[0], zv);
      s1 = mfma32(k1, qf[0], zv);
    }
    #pragma unroll
    for (int ks = 1; ks < 4; ks++) {
      int col = (ks*32 + hi*16) ^ rsw;
      bf16x8 k0 = *(const bf16x8*)(Kl + (size_t)l31*128 + col);
      bf16x8 k1 = *(const bf16x8*)(Kl + (size_t)(32 + l31)*128 + col);
      s0 = mfma32(k0, qf[ks], s0);
      s1 = mfma32(k1, qf[ks], s1);
    }
    __builtin_amdgcn_s_setprio(0);
  };

  // softmax + P->bf16 frags for one half (updates M, L, rescales o on demand)
  auto sm = [&](f32x16& s0, f32x16& s1, bf16x8* pf) {
    float m8[8];
    #pragma unroll
    for (int i = 0; i < 8; i++)
      m8[i] = fmaxf(fmaxf(s0[2*i], s0[2*i+1]), fmaxf(s1[2*i], s1[2*i+1]));
    float m4a = fmaxf(m8[0], m8[1]), m4b = fmaxf(m8[2], m8[3]);
    float m4c = fmaxf(m8[4], m8[5]), m4d = fmaxf(m8[6], m8[7]);
    float cm = fmaxf(fmaxf(m4a, m4b), fmaxf(m4c, m4d));
    cm = fmaxf(cm, __shfl_xor(cm, 32));
    if (!__all(cm <= M + 11.f)) {              // defer-max: P bounded by 2^11
      float nm = fmaxf(M, cm);
      float al = exp2fast(M - nm);
      M = nm;
      #pragma unroll
      for (int i = 0; i < 16; i++) { o0[i] *= al; o1[i] *= al; }
      L *= al;
    }
    #pragma unroll
    for (int i = 0; i < 16; i++) {
      s0[i] = exp2fast(s0[i] - M);
      s1[i] = exp2fast(s1[i] - M);
    }
    float r8[8];
    #pragma unroll
    for (int i = 0; i < 8; i++)
      r8[i] = (s0[2*i] + s0[2*i+1]) + (s1[2*i] + s1[2*i+1]);
    float r4a = r8[0] + r8[1], r4b = r8[2] + r8[3];
    float r4c = r8[4] + r8[5], r4d = r8[6] + r8[7];
    L += (r4a + r4b) + (r4c + r4d);            // own-half partial only

    u32 x0 = cvtpk(s0[0],  s0[1]),  x1 = cvtpk(s0[2],  s0[3]);
    u32 x2 = cvtpk(s0[4],  s0[5]),  x3 = cvtpk(s0[6],  s0[7]);
    u32 x4 = cvtpk(s0[8],  s0[9]),  x5 = cvtpk(s0[10], s0[11]);
    u32 x6 = cvtpk(s0[12], s0[13]), x7 = cvtpk(s0[14], s0[15]);
    u32 y0 = cvtpk(s1[0],  s1[1]),  y1 = cvtpk(s1[2],  s1[3]);
    u32 y2 = cvtpk(s1[4],  s1[5]),  y3 = cvtpk(s1[6],  s1[7]);
    u32 y4 = cvtpk(s1[8],  s1[9]),  y5 = cvtpk(s1[10], s1[11]);
    u32 y6 = cvtpk(s1[12], s1[13]), y7 = cvtpk(s1[14], s1[15]);
    // packed one-direction exchange: each shfl carries what the OTHER half
    // needs (lo receives partner x0.., hi receives partner x2..). Values are
    // identical to the R3-proven two-direction construction.
    u32 e0 = (u32)__shfl_xor((int)(hi ? x0 : x2), 32);
    u32 e1 = (u32)__shfl_xor((int)(hi ? x1 : x3), 32);
    u32 e2 = (u32)__shfl_xor((int)(hi ? x4 : x6), 32);
    u32 e3 = (u32)__shfl_xor((int)(hi ? x5 : x7), 32);
    u32 f0 = (u32)__shfl_xor((int)(hi ? y0 : y2), 32);
    u32 f1 = (u32)__shfl_xor((int)(hi ? y1 : y3), 32);
    u32 f2 = (u32)__shfl_xor((int)(hi ? y4 : y6), 32);
    u32 f3 = (u32)__shfl_xor((int)(hi ? y5 : y7), 32);
    pf[0] = hi ? mkfrag(e0, e1, x2, x3) : mkfrag(x0, x1, e0, e1);
    pf[1] = hi ? mkfrag(e2, e3, x6, x7) : mkfrag(x4, x5, e2, e3);
    pf[2] = hi ? mkfrag(f0, f1, y2, y3) : mkfrag(y0, y1, f0, f1);
    pf[3] = hi ? mkfrag(f2, f3, y6, y7) : mkfrag(y4, y5, f2, f3);
  };

  auto pv = [&](const char* Vl, const bf16x8* pf) {
    __builtin_amdgcn_s_setprio(1);
    #pragma unroll
    for (int s = 0; s < 4; s++) {
      int col = (s*32 + hi*16) ^ rsw;
      bf16x8 v0 = *(const bf16x8*)(Vl + (size_t)l31*128 + col);
      bf16x8 v1 = *(const bf16x8*)(Vl + (size_t)(32 + l31)*128 + col);
      o0 = mfma32(v0, pf[s], o0);
      o1 = mfma32(v1, pf[s], o1);
    }
    __builtin_amdgcn_s_setprio(0);
  };

  __syncthreads();                             // chunk 0 staged (drains vmcnt)

  for (int mc = 0; mc < 8; mc++) {             // 8 rounds of 128 keys
    char* cb = lds + ((mc & 1) << 15);
    if (mc < 7) stageChunk(lds + (((mc + 1) & 1) << 15), mc + 1);
    f32x16 sa0, sa1, sb0, sb1;
    bf16x8 pfA[4], pfB[4];
    qk(cb, sa0, sa1);                          // QK_A
    sm(sa0, sa1, pfA);                         // SM_A
    qk(cb + 8192, sb0, sb1);                   // QK_B
    pv(cb + 16384, pfA);                       // PV_A
    sm(sb0, sb1, pfB);                         // SM_B
    pv(cb + 24576, pfB);                       // PV_B
    __syncthreads();                           // releases cur buf, publishes next buf
  }

  // ---- epilogue: merge cross-half L, then O/L -> aoT[b][n][c=h*64+d] bf16 ----
  L += __shfl_xor(L, 32);
  float inv = 1.f / L;
  u16* dst = aoT + ((size_t)(b*1024 + q0 + l31))*512 + h*64;
  #pragma unroll
  for (int qd = 0; qd < 4; qd++) {
    uint2 val;
    val.x = cvtpk(o0[4*qd+0]*inv, o0[4*qd+1]*inv);
    val.y = cvtpk(o0[4*qd+2]*inv, o0[4*qd+3]*inv);
    *(uint2*)(dst + qd*8 + hi*4) = val;
  }
  #pragma unroll
  for (int qd = 0; qd < 4; qd++) {
    uint2 val;
    val.x = cvtpk(o1[4*qd+0]*inv, o1[4*qd+1]*inv);
    val.y = cvtpk(o1[4*qd+2]*inv, o1[4*qd+3]*inv);
    *(uint2*)(dst + 32 + qd*8 + hi*4) = val;
  }
}

extern "C" void kernel_launch(void* const* d_in, const int* in_sizes, int n_in,
                              void* d_out, int out_size, void* d_ws, size_t ws_size,
                              hipStream_t stream) {
  const float* x     = (const float*)d_in[0];
  const float* nsc   = (const float*)d_in[1];
  const float* nbi   = (const float*)d_in[2];
  const float* qkvw  = (const float*)d_in[3];
  const float* qkvb  = (const float*)d_in[4];
  const float* projw = (const float*)d_in[5];
  const float* projb = (const float*)d_in[6];
  float* out = (float*)d_out;

  char* ws = (char*)d_ws;
  float* meanr = (float*)ws;                          // 2 KB
  u16* qkvwb  = (u16*)(ws + 2048);                    // 1536*512*2
  u16* projwb = (u16*)(ws + 2048 + 1572864);          // 512*512*2
  char* p = ws + 2048 + 1572864 + 524288;
  u16* qT  = (u16*)p; p += 33554432;                  // [b][h][1024][64] bf16 (scaled)
  u16* kTb = (u16*)p; p += 33554432;                  // [b][h][1024][64] bf16
  u16* vb  = (u16*)p; p += 33554432;                  // [b][h][64][1024] bf16
  u16* xnT = (u16*)p;                                 // [b][1024][512] bf16, reused as aoT
  u16* aoT = xnT;

  k_gnstats<<<256, 256, 0, stream>>>(x, meanr);
  k_cvt<<<768, 256, 0, stream>>>(qkvw, qkvwb, 1536*512);
  k_cvt<<<256, 256, 0, stream>>>(projw, projwb, 512*512);
  k_norm_t<<<dim3(16, 8, 32), 256, 0, stream>>>(x, meanr, nsc, nbi, xnT);
  k_gemm<0><<<dim3(8, 12, 32), 256, 0, stream>>>(qkvwb, xnT, qkvb, nullptr,
                                                 qT, kTb, vb, nullptr);
  k_attn<<<dim3(4, 8, 32), 512, 0, stream>>>(qT, kTb, vb, aoT);
  k_gemm<1><<<dim3(8, 4, 32), 256, 0, stream>>>(projwb, aoT, projb, x,
                                                nullptr, nullptr, nullptr, out);
}